// Round 1
// baseline (334.535 us; speedup 1.0000x reference)
//
#include <hip/hip_runtime.h>

#define IN_FEATURES 8388608
#define NB 2048
#define TPB 256

// Pass 1: each block computes 6 partial dot-products over its strided chunk.
__global__ __launch_bounds__(TPB) void motor_partial(const float4* __restrict__ inp4,
                                                     const float4* __restrict__ w4,
                                                     float* __restrict__ ws) {
    const int NG = IN_FEATURES / 4;          // groups of 4 indices
    const int stride = NB * TPB;
    int g = blockIdx.x * TPB + threadIdx.x;

    float acc0 = 0.f, acc1 = 0.f, acc2 = 0.f, acc3 = 0.f, acc4 = 0.f, acc5 = 0.f;

    for (; g < NG; g += stride) {
        // input is [i][2] interleaved: 4 indices -> two consecutive float4s
        float4 i0 = inp4[2 * g];       // (x0, y0, x1, y1)
        float4 i1 = inp4[2 * g + 1];   // (x2, y2, x3, y3)
        float a0 = i0.x, b0 = i0.y, a1 = i0.z, b1 = i0.w;
        float a2 = i1.x, b2 = i1.y, a3 = i1.z, b3 = i1.w;

        const int rowstride = IN_FEATURES / 4;
        float4 w0 = w4[(size_t)0 * rowstride + g];
        float4 w1 = w4[(size_t)1 * rowstride + g];
        float4 w2 = w4[(size_t)2 * rowstride + g];
        float4 w3 = w4[(size_t)3 * rowstride + g];
        float4 w4v = w4[(size_t)4 * rowstride + g];
        float4 w5 = w4[(size_t)5 * rowstride + g];

        acc0 += w0.x * a0 + w0.y * a1 + w0.z * a2 + w0.w * a3;
        acc1 += w1.x * a0 + w1.y * a1 + w1.z * a2 + w1.w * a3;
        acc2 += w2.x * a0 + w2.y * a1 + w2.z * a2 + w2.w * a3;
        acc3 += w3.x * b0 + w3.y * b1 + w3.z * b2 + w3.w * b3;
        acc4 += w4v.x * b0 + w4v.y * b1 + w4v.z * b2 + w4v.w * b3;
        acc5 += w5.x * b0 + w5.y * b1 + w5.z * b2 + w5.w * b3;
    }

    float acc[6] = {acc0, acc1, acc2, acc3, acc4, acc5};

    // wave-64 shuffle reduction
    #pragma unroll
    for (int j = 0; j < 6; ++j) {
        float v = acc[j];
        #pragma unroll
        for (int off = 32; off > 0; off >>= 1)
            v += __shfl_down(v, off, 64);
        acc[j] = v;
    }

    __shared__ float sm[TPB / 64][6];
    const int lane = threadIdx.x & 63;
    const int wave = threadIdx.x >> 6;
    if (lane == 0) {
        #pragma unroll
        for (int j = 0; j < 6; ++j) sm[wave][j] = acc[j];
    }
    __syncthreads();
    if (threadIdx.x == 0) {
        #pragma unroll
        for (int j = 0; j < 6; ++j)
            ws[blockIdx.x * 6 + j] = sm[0][j] + sm[1][j] + sm[2][j] + sm[3][j];
    }
}

// Pass 2: one block, 6 waves; wave j reduces the NB partials for output j.
__global__ __launch_bounds__(384) void motor_final(const float* __restrict__ ws,
                                                   float* __restrict__ out) {
    const int j = threadIdx.x >> 6;   // wave index = output index (0..5)
    const int lane = threadIdx.x & 63;
    float v = 0.f;
    for (int k = lane; k < NB; k += 64) v += ws[k * 6 + j];
    #pragma unroll
    for (int off = 32; off > 0; off >>= 1)
        v += __shfl_down(v, off, 64);
    if (lane == 0) out[j] = v;
}

extern "C" void kernel_launch(void* const* d_in, const int* in_sizes, int n_in,
                              void* d_out, int out_size, void* d_ws, size_t ws_size,
                              hipStream_t stream) {
    const float4* inp4 = (const float4*)d_in[0];   // [IN_FEATURES, 2] fp32
    const float4* w4   = (const float4*)d_in[1];   // [6, IN_FEATURES] fp32
    float* ws  = (float*)d_ws;                     // NB*6 floats of scratch
    float* out = (float*)d_out;                    // [6] fp32

    motor_partial<<<NB, TPB, 0, stream>>>(inp4, w4, ws);
    motor_final<<<1, 384, 0, stream>>>(ws, out);
}

// Round 3
// 298.570 us; speedup vs baseline: 1.1205x; 1.1205x over previous
//
#include <hip/hip_runtime.h>

#define IN_FEATURES 8388608
#define NG (IN_FEATURES / 4)   // 2,097,152 groups of 4 indices
#define TPB 256
#define NB (NG / TPB)          // 8192 blocks -> exactly one group per thread

typedef float f32x4 __attribute__((ext_vector_type(4)));  // clang vector: OK for nontemporal builtin

// Pass 1: one 4-index group per thread. 8 independent float4 loads issued
// back-to-back (no loop, no per-iteration vmcnt(0) stalls), then 6 partial
// dots, wave-64 shuffle reduce, cross-wave LDS reduce, one store per output.
__global__ __launch_bounds__(TPB) void motor_partial(const f32x4* __restrict__ inp4,
                                                     const f32x4* __restrict__ w4,
                                                     float* __restrict__ ws) {
    const size_t g = (size_t)blockIdx.x * TPB + threadIdx.x;

    // input is [i][2] interleaved: 4 indices -> two consecutive float4s
    f32x4 i0  = __builtin_nontemporal_load(inp4 + 2 * g);
    f32x4 i1  = __builtin_nontemporal_load(inp4 + 2 * g + 1);
    f32x4 w0  = __builtin_nontemporal_load(w4 + 0 * (size_t)NG + g);
    f32x4 w1  = __builtin_nontemporal_load(w4 + 1 * (size_t)NG + g);
    f32x4 w2  = __builtin_nontemporal_load(w4 + 2 * (size_t)NG + g);
    f32x4 w3  = __builtin_nontemporal_load(w4 + 3 * (size_t)NG + g);
    f32x4 w4v = __builtin_nontemporal_load(w4 + 4 * (size_t)NG + g);
    f32x4 w5  = __builtin_nontemporal_load(w4 + 5 * (size_t)NG + g);

    const float a0 = i0.x, b0 = i0.y, a1 = i0.z, b1 = i0.w;
    const float a2 = i1.x, b2 = i1.y, a3 = i1.z, b3 = i1.w;

    float acc[6];
    acc[0] = w0.x * a0 + w0.y * a1 + w0.z * a2 + w0.w * a3;
    acc[1] = w1.x * a0 + w1.y * a1 + w1.z * a2 + w1.w * a3;
    acc[2] = w2.x * a0 + w2.y * a1 + w2.z * a2 + w2.w * a3;
    acc[3] = w3.x * b0 + w3.y * b1 + w3.z * b2 + w3.w * b3;
    acc[4] = w4v.x * b0 + w4v.y * b1 + w4v.z * b2 + w4v.w * b3;
    acc[5] = w5.x * b0 + w5.y * b1 + w5.z * b2 + w5.w * b3;

    // wave-64 shuffle reduction
    #pragma unroll
    for (int j = 0; j < 6; ++j) {
        float v = acc[j];
        #pragma unroll
        for (int off = 32; off > 0; off >>= 1)
            v += __shfl_down(v, off, 64);
        acc[j] = v;
    }

    __shared__ float sm[TPB / 64][6];
    const int lane = threadIdx.x & 63;
    const int wave = threadIdx.x >> 6;
    if (lane == 0) {
        #pragma unroll
        for (int j = 0; j < 6; ++j) sm[wave][j] = acc[j];
    }
    __syncthreads();
    // transposed partial layout: ws[j*NB + block] -> coalesced final pass
    if (threadIdx.x < 6) {
        const int j = threadIdx.x;
        ws[(size_t)j * NB + blockIdx.x] = sm[0][j] + sm[1][j] + sm[2][j] + sm[3][j];
    }
}

// Pass 2: one block, 6 waves; wave j reduces the NB partials for output j
// with coalesced float4 loads.
__global__ __launch_bounds__(384) void motor_final(const float* __restrict__ ws,
                                                   float* __restrict__ out) {
    const int j = threadIdx.x >> 6;   // wave index = output index (0..5)
    const int lane = threadIdx.x & 63;
    const f32x4* p = (const f32x4*)(ws + (size_t)j * NB);
    float v = 0.f;
    #pragma unroll
    for (int k = 0; k < NB / 4 / 64; ++k) {   // 32 iterations
        f32x4 t = p[(size_t)k * 64 + lane];
        v += (t.x + t.y) + (t.z + t.w);
    }
    #pragma unroll
    for (int off = 32; off > 0; off >>= 1)
        v += __shfl_down(v, off, 64);
    if (lane == 0) out[j] = v;
}

extern "C" void kernel_launch(void* const* d_in, const int* in_sizes, int n_in,
                              void* d_out, int out_size, void* d_ws, size_t ws_size,
                              hipStream_t stream) {
    const f32x4* inp4 = (const f32x4*)d_in[0];   // [IN_FEATURES, 2] fp32
    const f32x4* w4   = (const f32x4*)d_in[1];   // [6, IN_FEATURES] fp32
    float* ws  = (float*)d_ws;                   // NB*6 floats of scratch
    float* out = (float*)d_out;                  // [6] fp32

    motor_partial<<<NB, TPB, 0, stream>>>(inp4, w4, ws);
    motor_final<<<1, 384, 0, stream>>>(ws, out);
}